// Round 8
// baseline (332.085 us; speedup 1.0000x reference)
//
#include <hip/hip_runtime.h>
#include <math.h>

#define BB 32
#define DD 2048
#define NKVH 4
#define HDIM 128
#define MAXS 4096
#define FFD 8192
#define POS 4095
#define EPSV 1e-5f
#define SCALE 0.08838834764831845f
#define ASPLIT 16
#define SPOS 256   // positions per split

// workspace offsets (floats)
#define OFF_QT   0u        // 32 x 2048 q (NORMAL layout, atomic target)
#define OFF_KT   65536u    // 512 x 32 (transposed)
#define OFF_VT   81920u    // 512 x 32
#define OFF_G1   98304u    // 8192 x 32
#define OFF_G2   360448u   // 8192 x 32
#define ZERO_N   622592u   // contiguous atomic-target region [0, ZERO_N)
#define OFF_XAT  622592u   // 2048 x 32
#define OFF_PML  720896u   // 32*4*16*4 x {m,l} = 16384
#define OFF_PACC 737280u   // 32*4*16*4 x 128 = 1048576
#define OFF_YT   1785856u  // 2048 x 32
#define OFF_H    1851392u  // 32 x 2048 (normal)
#define OFF_XFT  1916928u  // 2048 x 32
#define OFF_KFIX 1982464u  // 32 x 16 x 512 (last-16-pos K records, 4095 patched)
#define OFF_VFIX 2244608u  // 32 x 16 x 512

#define REP32(M) M(0) M(1) M(2) M(3) M(4) M(5) M(6) M(7) M(8) M(9) M(10) M(11) M(12) M(13) M(14) M(15) M(16) M(17) M(18) M(19) M(20) M(21) M(22) M(23) M(24) M(25) M(26) M(27) M(28) M(29) M(30) M(31)
#define REP32A(M,X) M(0,X) M(1,X) M(2,X) M(3,X) M(4,X) M(5,X) M(6,X) M(7,X) M(8,X) M(9,X) M(10,X) M(11,X) M(12,X) M(13,X) M(14,X) M(15,X) M(16,X) M(17,X) M(18,X) M(19,X) M(20,X) M(21,X) M(22,X) M(23,X) M(24,X) M(25,X) M(26,X) M(27,X) M(28,X) M(29,X) M(30,X) M(31,X)

#define DECLA(i) float a##i = 0.f;
#define FMA1(i,k) a##i = fmaf(ap[(k)*32 + (i)], w##k, a##i);
#define STORET(i) tl[i] = a##i;
#define ATOMN(i) atomicAdd(C + (size_t)(i)*N + n, a##i);
#define LDW(k) float w##k = Wp[(size_t)N * (k)];

// 32-batch GEMV: C[b][n] += sum_d At[d][b] * W[d][n].
// 8 weight loads in flight per thread; TOUT: transposed C via LDS-staged atomics.
template<int N, int CH, bool TOUT>
__device__ __forceinline__ void gemv_body(const float* __restrict__ At,
                                          const float* __restrict__ W,
                                          float* __restrict__ C, int colblk,
                                          float* tile) {
    int tid = (int)threadIdx.x;
    int n = colblk * 256 + tid;
    int d0 = blockIdx.y * CH;
    const float* Wp = W + (size_t)d0 * N + n;
    const float* ap = At + (size_t)d0 * 32;
    REP32(DECLA)
#pragma unroll 2
    for (int dd = 0; dd < CH; dd += 8) {
        LDW(0) LDW(1) LDW(2) LDW(3) LDW(4) LDW(5) LDW(6) LDW(7)
        REP32A(FMA1, 0)
        REP32A(FMA1, 1)
        REP32A(FMA1, 2)
        REP32A(FMA1, 3)
        REP32A(FMA1, 4)
        REP32A(FMA1, 5)
        REP32A(FMA1, 6)
        REP32A(FMA1, 7)
        Wp += (size_t)N * 8;
        ap += 256;
    }
    if constexpr (TOUT) {
        float* tl = tile + tid * 33;
        REP32(STORET)
        __syncthreads();
        float* cb = C + (size_t)colblk * 256 * 32;
#pragma unroll
        for (int i = 0; i < 32; ++i) {
            int f = i * 256 + tid;
            atomicAdd(cb + f, tile[(f >> 5) * 33 + (f & 31)]);
        }
    } else {
        REP32(ATOMN)
    }
}

template<int N, int CH, bool TOUT>
__global__ __launch_bounds__(256) void gemv32_kernel(const float* __restrict__ At,
                                                     const float* __restrict__ W,
                                                     float* __restrict__ C) {
    if constexpr (TOUT) {
        __shared__ float tile[256 * 33];
        gemv_body<N, CH, true>(At, W, C, blockIdx.x, tile);
    } else {
        gemv_body<N, CH, false>(At, W, C, blockIdx.x, nullptr);
    }
}

template<int N, int CH, int HALF>
__global__ __launch_bounds__(256) void gemv32_dual_kernel(const float* __restrict__ At,
        const float* __restrict__ W0, const float* __restrict__ W1,
        float* __restrict__ C0, float* __restrict__ C1) {
    __shared__ float tile[256 * 33];
    int bx = blockIdx.x;
    if (bx < HALF) gemv_body<N, CH, true>(At, W0, C0, bx, tile);
    else           gemv_body<N, CH, true>(At, W1, C1, bx - HALF, tile);
}

__global__ void zero_kernel(float* __restrict__ p) {
    p[blockIdx.x * 256 + threadIdx.x] = 0.f;
}

// rmsnorm row b: outT[d][b] = norm; cpy[b][d] = raw input (residual)
__global__ void rmsnorm_kernel(const float* __restrict__ in, const float* __restrict__ g,
                               float* __restrict__ outT, float* __restrict__ cpy) {
    int b = blockIdx.x;
    int tid = threadIdx.x; // 256
    const float* row = in + b * DD;
    float v[8];
    float ss = 0.f;
#pragma unroll
    for (int i = 0; i < 8; ++i) { v[i] = row[tid + i * 256]; ss += v[i] * v[i]; }
#pragma unroll
    for (int off = 32; off; off >>= 1) ss += __shfl_xor(ss, off);
    __shared__ float red[4];
    if ((tid & 63) == 0) red[tid >> 6] = ss;
    __syncthreads();
    ss = red[0] + red[1] + red[2] + red[3];
    float scale = rsqrtf(ss * (1.f / DD) + EPSV);
#pragma unroll
    for (int i = 0; i < 8; ++i) {
        int idx = tid + i * 256;
        outT[(size_t)idx * 32 + b] = v[i] * g[idx] * scale;
        if (cpy) cpy[b * DD + idx] = v[i];
    }
}

// materialize last-16-position K/V records [b][16][512]; pos 4095 is roped
// on the fly from kT/vT (reference ropes BOTH k and v; cache never mutated).
__global__ void fixrope_kernel(const float* __restrict__ kc, const float* __restrict__ vc,
                               const float* __restrict__ kT, const float* __restrict__ vT,
                               const float* __restrict__ cosb, const float* __restrict__ sinb,
                               float* __restrict__ kfix, float* __restrict__ vfix) {
    int idx = blockIdx.x * 256 + threadIdx.x;  // 32*16*512 = 262144
    int b = idx >> 13, rem = idx & 8191;
    int pos = rem >> 9, col = rem & 511;
    int gpos = 4080 + pos;
    float kv, vv;
    if (gpos == POS) {
        int d = col & 127, i = d >> 1;
        float c = cosb[i], s = sinb[i];
        int colp = col & ~1;
        float k0 = kT[(size_t)colp * 32 + b], k1 = kT[(size_t)(colp + 1) * 32 + b];
        float v0 = vT[(size_t)colp * 32 + b], v1 = vT[(size_t)(colp + 1) * 32 + b];
        if (d & 1) { kv = k0 * s + k1 * c; vv = v0 * s + v1 * c; }
        else       { kv = k0 * c - k1 * s; vv = v0 * c - v1 * s; }
    } else {
        size_t o = ((size_t)(b * MAXS + gpos)) * 512 + col;
        kv = kc[o]; vv = vc[o];
    }
    kfix[idx] = kv; vfix[idx] = vv;
}

// ---- deep-MLP attention: grid 2048 = (b, kvh, 16 splits of 256 pos) ----
// QK: one position/thread; 8 float4 K loads always in flight (ping-pong A/B).
// PV: thread=(tsub,q4); 8 float4 V loads in flight. No DMA, 3 barriers total.

#define QKSTEP(KK,D0) \
    s0 = fmaf(KK.x, q_s[0][D0], s0); s0 = fmaf(KK.y, q_s[0][(D0)+1], s0); \
    s0 = fmaf(KK.z, q_s[0][(D0)+2], s0); s0 = fmaf(KK.w, q_s[0][(D0)+3], s0); \
    s1 = fmaf(KK.x, q_s[1][D0], s1); s1 = fmaf(KK.y, q_s[1][(D0)+1], s1); \
    s1 = fmaf(KK.z, q_s[1][(D0)+2], s1); s1 = fmaf(KK.w, q_s[1][(D0)+3], s1); \
    s2 = fmaf(KK.x, q_s[2][D0], s2); s2 = fmaf(KK.y, q_s[2][(D0)+1], s2); \
    s2 = fmaf(KK.z, q_s[2][(D0)+2], s2); s2 = fmaf(KK.w, q_s[2][(D0)+3], s2); \
    s3 = fmaf(KK.x, q_s[3][D0], s3); s3 = fmaf(KK.y, q_s[3][(D0)+1], s3); \
    s3 = fmaf(KK.z, q_s[3][(D0)+2], s3); s3 = fmaf(KK.w, q_s[3][(D0)+3], s3);

#define QKLOAD(S,JB) \
    S##0 = *(const float4*)(krow + (JB)*32 + 0);  S##1 = *(const float4*)(krow + (JB)*32 + 4); \
    S##2 = *(const float4*)(krow + (JB)*32 + 8);  S##3 = *(const float4*)(krow + (JB)*32 + 12); \
    S##4 = *(const float4*)(krow + (JB)*32 + 16); S##5 = *(const float4*)(krow + (JB)*32 + 20); \
    S##6 = *(const float4*)(krow + (JB)*32 + 24); S##7 = *(const float4*)(krow + (JB)*32 + 28);

#define QKFMA(S,JB) \
    QKSTEP(S##0,(JB)*32+0)  QKSTEP(S##1,(JB)*32+4)  QKSTEP(S##2,(JB)*32+8)  QKSTEP(S##3,(JB)*32+12) \
    QKSTEP(S##4,(JB)*32+16) QKSTEP(S##5,(JB)*32+20) QKSTEP(S##6,(JB)*32+24) QKSTEP(S##7,(JB)*32+28)

#define PVSTEP(VV,P0,P1,P2,P3) \
    a0.x = fmaf(P0, VV.x, a0.x); a0.y = fmaf(P0, VV.y, a0.y); a0.z = fmaf(P0, VV.z, a0.z); a0.w = fmaf(P0, VV.w, a0.w); \
    a1.x = fmaf(P1, VV.x, a1.x); a1.y = fmaf(P1, VV.y, a1.y); a1.z = fmaf(P1, VV.z, a1.z); a1.w = fmaf(P1, VV.w, a1.w); \
    a2.x = fmaf(P2, VV.x, a2.x); a2.y = fmaf(P2, VV.y, a2.y); a2.z = fmaf(P2, VV.z, a2.z); a2.w = fmaf(P2, VV.w, a2.w); \
    a3.x = fmaf(P3, VV.x, a3.x); a3.y = fmaf(P3, VV.y, a3.y); a3.z = fmaf(P3, VV.z, a3.z); a3.w = fmaf(P3, VV.w, a3.w);

#define PVLOAD(S,JB) \
    S##0 = *(const float4*)(vbase + (size_t)((JB)*8+0)*512); S##1 = *(const float4*)(vbase + (size_t)((JB)*8+1)*512); \
    S##2 = *(const float4*)(vbase + (size_t)((JB)*8+2)*512); S##3 = *(const float4*)(vbase + (size_t)((JB)*8+3)*512); \
    S##4 = *(const float4*)(vbase + (size_t)((JB)*8+4)*512); S##5 = *(const float4*)(vbase + (size_t)((JB)*8+5)*512); \
    S##6 = *(const float4*)(vbase + (size_t)((JB)*8+6)*512); S##7 = *(const float4*)(vbase + (size_t)((JB)*8+7)*512);

#define PVFMA(S,JB) { \
    int tl = tsub * 32 + (JB) * 8; \
    float4 pa0 = *(const float4*)&p_s[0][tl], pb0 = *(const float4*)&p_s[0][tl + 4]; \
    float4 pa1 = *(const float4*)&p_s[1][tl], pb1 = *(const float4*)&p_s[1][tl + 4]; \
    float4 pa2 = *(const float4*)&p_s[2][tl], pb2 = *(const float4*)&p_s[2][tl + 4]; \
    float4 pa3 = *(const float4*)&p_s[3][tl], pb3 = *(const float4*)&p_s[3][tl + 4]; \
    PVSTEP(S##0, pa0.x, pa1.x, pa2.x, pa3.x) \
    PVSTEP(S##1, pa0.y, pa1.y, pa2.y, pa3.y) \
    PVSTEP(S##2, pa0.z, pa1.z, pa2.z, pa3.z) \
    PVSTEP(S##3, pa0.w, pa1.w, pa2.w, pa3.w) \
    PVSTEP(S##4, pb0.x, pb1.x, pb2.x, pb3.x) \
    PVSTEP(S##5, pb0.y, pb1.y, pb2.y, pb3.y) \
    PVSTEP(S##6, pb0.z, pb1.z, pb2.z, pb3.z) \
    PVSTEP(S##7, pb0.w, pb1.w, pb2.w, pb3.w) }

__global__ __launch_bounds__(256) void attn_mlp_kernel(
    const float* __restrict__ qn, const float* __restrict__ kc, const float* __restrict__ vc,
    const float* __restrict__ kfix, const float* __restrict__ vfix,
    float* __restrict__ pml, float* __restrict__ pacc) {
    int bid = blockIdx.x;
    int split = bid & 15, kvh = (bid >> 4) & 3, b = bid >> 6;
    int tid = threadIdx.x;
    __shared__ float q_s[4][HDIM];       // 2 KB
    __shared__ float p_s[4][SPOS];       // 4 KB
    __shared__ float red[8][4][HDIM];    // 16 KB
    for (int i = tid; i < 512; i += 256)
        q_s[i >> 7][i & 127] = qn[(size_t)b * DD + kvh * 512 + i];
    __syncthreads();
    int t0 = split * SPOS;
    // ---- QK: one position per thread, pipelined 8-deep loads ----
    {
        int t = t0 + tid;
        const float* krow = (t == POS)
            ? kfix + (size_t)b * 8192 + 15 * 512 + kvh * HDIM
            : kc + ((size_t)(b * MAXS + t) * NKVH + kvh) * HDIM;
        float s0 = 0.f, s1 = 0.f, s2 = 0.f, s3 = 0.f;
        float4 A0, A1, A2, A3, A4, A5, A6, A7, B0, B1, B2, B3, B4, B5, B6, B7;
        QKLOAD(A, 0)
        QKLOAD(B, 1) QKFMA(A, 0)
        QKLOAD(A, 2) QKFMA(B, 1)
        QKLOAD(B, 3) QKFMA(A, 2)
        QKFMA(B, 3)
        p_s[0][tid] = s0 * SCALE; p_s[1][tid] = s1 * SCALE;
        p_s[2][tid] = s2 * SCALE; p_s[3][tid] = s3 * SCALE;
    }
    __syncthreads();
    // ---- softmax: wave w handles local head w over 256 positions ----
    {
        int w = tid >> 6, lane = tid & 63;
        float e0 = p_s[w][lane], e1 = p_s[w][lane + 64];
        float e2 = p_s[w][lane + 128], e3 = p_s[w][lane + 192];
        float m = fmaxf(fmaxf(e0, e1), fmaxf(e2, e3));
#pragma unroll
        for (int off = 32; off; off >>= 1) m = fmaxf(m, __shfl_xor(m, off));
        e0 = __expf(e0 - m); e1 = __expf(e1 - m);
        e2 = __expf(e2 - m); e3 = __expf(e3 - m);
        p_s[w][lane] = e0; p_s[w][lane + 64] = e1;
        p_s[w][lane + 128] = e2; p_s[w][lane + 192] = e3;
        float l = e0 + e1 + e2 + e3;
#pragma unroll
        for (int off = 32; off; off >>= 1) l += __shfl_xor(l, off);
        if (lane == 0) {
            int idx = ((b * NKVH + kvh) * ASPLIT + split) * 4 + w;
            pml[2 * idx] = m; pml[2 * idx + 1] = l;
        }
    }
    __syncthreads();
    // ---- PV: thread=(tsub 0..7, q4 0..31), pipelined 8-deep loads ----
    {
        int tsub = tid >> 5, q4 = tid & 31;
        const float* vbase = vc + ((size_t)(b * MAXS + t0 + tsub * 32) * NKVH + kvh) * HDIM + q4 * 4;
        bool lastt = (split == ASPLIT - 1 && tsub == 7);
        float4 a0 = {0, 0, 0, 0}, a1 = a0, a2 = a0, a3 = a0;
        float4 A0, A1, A2, A3, A4, A5, A6, A7, B0, B1, B2, B3, B4, B5, B6, B7;
        PVLOAD(A, 0)
        PVLOAD(B, 1) PVFMA(A, 0)
        PVLOAD(A, 2) PVFMA(B, 1)
        PVLOAD(B, 3)
        if (lastt)   // pos 4095 comes from the roped record (cache unmutated)
            B7 = *(const float4*)(vfix + (size_t)b * 8192 + 15 * 512 + kvh * HDIM + q4 * 4);
        PVFMA(A, 2)
        PVFMA(B, 3)
        *(float4*)&red[tsub][0][q4 * 4] = a0;
        *(float4*)&red[tsub][1][q4 * 4] = a1;
        *(float4*)&red[tsub][2][q4 * 4] = a2;
        *(float4*)&red[tsub][3][q4 * 4] = a3;
    }
    __syncthreads();
    if (tid < 128) {
        int h = tid >> 5, qq = tid & 31;
        float4 s = {0, 0, 0, 0};
#pragma unroll
        for (int r = 0; r < 8; ++r) {
            float4 t4 = *(const float4*)&red[r][h][qq * 4];
            s.x += t4.x; s.y += t4.y; s.z += t4.z; s.w += t4.w;
        }
        int idx = ((b * NKVH + kvh) * ASPLIT + split) * 4 + h;
        *(float4*)(pacc + (size_t)idx * HDIM + qq * 4) = s;
    }
}

// combine split partials: grid 512 = (b, h), 128 threads; writes yT
__global__ void attn_combine_kernel(const float* __restrict__ pml,
                                    const float* __restrict__ pacc, float* __restrict__ yT) {
    int bid = blockIdx.x;
    int b = bid >> 4, h = bid & 15;
    int kvh = h >> 2, hl = h & 3;
    int d = threadIdx.x;
    float M = -INFINITY;
#pragma unroll 8
    for (int s = 0; s < ASPLIT; ++s)
        M = fmaxf(M, pml[(((b * NKVH + kvh) * ASPLIT + s) * 4 + hl) * 2]);
    float denom = 0.f, acc = 0.f;
#pragma unroll 4
    for (int s = 0; s < ASPLIT; ++s) {
        int idx = ((b * NKVH + kvh) * ASPLIT + s) * 4 + hl;
        float e = __expf(pml[2 * idx] - M);
        denom += pml[2 * idx + 1] * e;
        acc += e * pacc[(size_t)idx * HDIM + d];
    }
    yT[(size_t)(h * HDIM + d) * 32 + b] = acc / denom;
}

__global__ void silu_mul_kernel(float* __restrict__ g1, const float* __restrict__ g2) {
    int i = blockIdx.x * 256 + threadIdx.x; // 262144
    float a = g1[i], bb = g2[i];
    g1[i] = a * bb / (1.f + __expf(-a));
}

extern "C" void kernel_launch(void* const* d_in, const int* in_sizes, int n_in,
                              void* d_out, int out_size, void* d_ws, size_t ws_size,
                              hipStream_t stream) {
    (void)in_sizes; (void)n_in; (void)out_size; (void)ws_size;
    const float* x    = (const float*)d_in[0];
    const float* cosb = (const float*)d_in[1];
    const float* sinb = (const float*)d_in[2];
    const float* kc   = (const float*)d_in[3];
    const float* vc   = (const float*)d_in[4];
    const float* wra  = (const float*)d_in[5];
    const float* wq   = (const float*)d_in[6];
    const float* wk   = (const float*)d_in[7];
    const float* wv   = (const float*)d_in[8];
    const float* wo   = (const float*)d_in[9];
    const float* wrf  = (const float*)d_in[10];
    const float* w1   = (const float*)d_in[11];
    const float* w2   = (const float*)d_in[12];
    const float* w3   = (const float*)d_in[13];
    float* out = (float*)d_out;
    float* ws  = (float*)d_ws;

    float* qn   = ws + OFF_QT;
    float* kT   = ws + OFF_KT;
    float* vT   = ws + OFF_VT;
    float* g1T  = ws + OFF_G1;
    float* g2T  = ws + OFF_G2;
    float* xaT  = ws + OFF_XAT;
    float* pml  = ws + OFF_PML;
    float* pacc = ws + OFF_PACC;
    float* yT   = ws + OFF_YT;
    float* h    = ws + OFF_H;
    float* xfT  = ws + OFF_XFT;
    float* kfix = ws + OFF_KFIX;
    float* vfix = ws + OFF_VFIX;

    // zero all atomic-accumulated buffers (qn,kT,vT,g1,g2 contiguous)
    zero_kernel<<<ZERO_N / 256, 256, 0, stream>>>(ws);

    // xaT = rmsnorm(x)^T, h = x
    rmsnorm_kernel<<<32, 256, 0, stream>>>(x, wra, xaT, h);
    // q (NORMAL layout), k/v (transposed for rope)
    gemv32_kernel<2048, 64, false><<<dim3(8, 32), 256, 0, stream>>>(xaT, wq, qn);
    gemv32_dual_kernel<512, 64, 2><<<dim3(4, 32), 256, 0, stream>>>(xaT, wk, wv, kT, vT);
    // patched last-16 records with rope applied to pos 4095 (cache NOT mutated)
    fixrope_kernel<<<1024, 256, 0, stream>>>(kc, vc, kT, vT, cosb, sinb, kfix, vfix);
    // attention (deep-MLP register-pipelined)
    attn_mlp_kernel<<<2048, 256, 0, stream>>>(qn, kc, vc, kfix, vfix, pml, pacc);
    attn_combine_kernel<<<512, 128, 0, stream>>>(pml, pacc, yT);
    // h = x + y @ wo
    gemv32_kernel<2048, 64, false><<<dim3(8, 32), 256, 0, stream>>>(yT, wo, h);
    // xfT = rmsnorm(h)^T, out = h
    rmsnorm_kernel<<<32, 256, 0, stream>>>(h, wrf, xfT, out);
    // g1 = xf@w1, g2 = xf@w2 (transposed outputs)
    gemv32_dual_kernel<8192, 128, 32><<<dim3(64, 16), 256, 0, stream>>>(xfT, w1, w2, g1T, g2T);
    // g1 = silu(g1)*g2 (elementwise, layout-agnostic)
    silu_mul_kernel<<<1024, 256, 0, stream>>>(g1T, g2T);
    // out += g1 @ w3
    gemv32_kernel<2048, 256, false><<<dim3(8, 32), 256, 0, stream>>>(g1T, w3, out);
}

// Round 9
// 301.666 us; speedup vs baseline: 1.1008x; 1.1008x over previous
//
#include <hip/hip_runtime.h>
#include <math.h>

#define BB 32
#define DD 2048
#define NKVH 4
#define HDIM 128
#define MAXS 4096
#define FFD 8192
#define POS 4095
#define EPSV 1e-5f
#define SCALE 0.08838834764831845f
#define ASPLIT 32
#define SPOS 128   // positions per split

// workspace offsets (floats)
#define OFF_QT   0u        // 32 x 2048 q (NORMAL layout, atomic target)
#define OFF_KT   65536u    // 512 x 32 (transposed)
#define OFF_VT   81920u    // 512 x 32
#define OFF_G1   98304u    // 8192 x 32
#define OFF_G2   360448u   // 8192 x 32
#define ZERO_N   622592u   // contiguous atomic-target region [0, ZERO_N)
#define OFF_XAT  622592u   // 2048 x 32
#define OFF_PML  720896u   // 32*32*16 x {m,l} = 32768
#define OFF_PACC 753664u   // 32*32*16 x 128 = 2097152
#define OFF_YT   2850816u  // 2048 x 32
#define OFF_H    2916352u  // 32 x 2048 (normal)
#define OFF_XFT  2981888u  // 2048 x 32
#define OFF_KFIX 3047424u  // 32 x 16 x 512 (last-16-pos K records, 4095 patched)
#define OFF_VFIX 3309568u  // 32 x 16 x 512

#define VM_WAIT8  asm volatile("s_waitcnt vmcnt(8)" ::: "memory")
#define VM_WAIT0  asm volatile("s_waitcnt vmcnt(0)" ::: "memory")
#define LG_WAIT0  asm volatile("s_waitcnt lgkmcnt(0)" ::: "memory")
#define SCHED0    __builtin_amdgcn_sched_barrier(0)
#define SBAR      __builtin_amdgcn_s_barrier()

#define REP32(M) M(0) M(1) M(2) M(3) M(4) M(5) M(6) M(7) M(8) M(9) M(10) M(11) M(12) M(13) M(14) M(15) M(16) M(17) M(18) M(19) M(20) M(21) M(22) M(23) M(24) M(25) M(26) M(27) M(28) M(29) M(30) M(31)
#define REP32A(M,X) M(0,X) M(1,X) M(2,X) M(3,X) M(4,X) M(5,X) M(6,X) M(7,X) M(8,X) M(9,X) M(10,X) M(11,X) M(12,X) M(13,X) M(14,X) M(15,X) M(16,X) M(17,X) M(18,X) M(19,X) M(20,X) M(21,X) M(22,X) M(23,X) M(24,X) M(25,X) M(26,X) M(27,X) M(28,X) M(29,X) M(30,X) M(31,X)

#define DECLA(i) float a##i = 0.f;
#define FMA1(i,k) a##i = fmaf(ap[(k)*32 + (i)], w##k, a##i);
#define STORET(i) tl[i] = a##i;
#define ATOMN(i) atomicAdd(C + (size_t)(i)*N + n, a##i);

// 32-batch GEMV: C[b][n] += sum_d At[d][b] * W[d][n].  (r2-proven config)
// Weight stream loads are NON-TEMPORAL: weights are read once; keep them from
// evicting the KV cache out of L3 between graph replays.
template<int N, int CH, bool TOUT>
__device__ __forceinline__ void gemv_body(const float* __restrict__ At,
                                          const float* __restrict__ W,
                                          float* __restrict__ C, int colblk,
                                          float* tile) {
    int tid = (int)threadIdx.x;
    int n = colblk * 256 + tid;
    int d0 = blockIdx.y * CH;
    const float* Wp = W + (size_t)d0 * N + n;
    const float* ap = At + (size_t)d0 * 32;
    REP32(DECLA)
#pragma unroll 4
    for (int dd = 0; dd < CH; dd += 4) {
        float w0 = __builtin_nontemporal_load(Wp);
        float w1 = __builtin_nontemporal_load(Wp + (size_t)N);
        float w2 = __builtin_nontemporal_load(Wp + (size_t)N * 2);
        float w3 = __builtin_nontemporal_load(Wp + (size_t)N * 3);
        REP32A(FMA1, 0)
        REP32A(FMA1, 1)
        REP32A(FMA1, 2)
        REP32A(FMA1, 3)
        Wp += (size_t)N * 4;
        ap += 128;
    }
    if constexpr (TOUT) {
        float* tl = tile + tid * 33;
        REP32(STORET)
        __syncthreads();
        float* cb = C + (size_t)colblk * 256 * 32;
#pragma unroll
        for (int i = 0; i < 32; ++i) {
            int f = i * 256 + tid;
            atomicAdd(cb + f, tile[(f >> 5) * 33 + (f & 31)]);
        }
    } else {
        REP32(ATOMN)
    }
}

template<int N, int CH, bool TOUT>
__global__ __launch_bounds__(256) void gemv32_kernel(const float* __restrict__ At,
                                                     const float* __restrict__ W,
                                                     float* __restrict__ C) {
    if constexpr (TOUT) {
        __shared__ float tile[256 * 33];
        gemv_body<N, CH, true>(At, W, C, blockIdx.x, tile);
    } else {
        gemv_body<N, CH, false>(At, W, C, blockIdx.x, nullptr);
    }
}

template<int N, int CH, int HALF>
__global__ __launch_bounds__(256) void gemv32_dual_kernel(const float* __restrict__ At,
        const float* __restrict__ W0, const float* __restrict__ W1,
        float* __restrict__ C0, float* __restrict__ C1) {
    __shared__ float tile[256 * 33];
    int bx = blockIdx.x;
    if (bx < HALF) gemv_body<N, CH, true>(At, W0, C0, bx, tile);
    else           gemv_body<N, CH, true>(At, W1, C1, bx - HALF, tile);
}

__global__ void zero_kernel(float* __restrict__ p) {
    p[blockIdx.x * 256 + threadIdx.x] = 0.f;
}

// rmsnorm row b: outT[d][b] = norm; cpy[b][d] = raw input (residual)
__global__ void rmsnorm_kernel(const float* __restrict__ in, const float* __restrict__ g,
                               float* __restrict__ outT, float* __restrict__ cpy) {
    int b = blockIdx.x;
    int tid = threadIdx.x; // 256
    const float* row = in + b * DD;
    float v[8];
    float ss = 0.f;
#pragma unroll
    for (int i = 0; i < 8; ++i) { v[i] = row[tid + i * 256]; ss += v[i] * v[i]; }
#pragma unroll
    for (int off = 32; off; off >>= 1) ss += __shfl_xor(ss, off);
    __shared__ float red[4];
    if ((tid & 63) == 0) red[tid >> 6] = ss;
    __syncthreads();
    ss = red[0] + red[1] + red[2] + red[3];
    float scale = rsqrtf(ss * (1.f / DD) + EPSV);
#pragma unroll
    for (int i = 0; i < 8; ++i) {
        int idx = tid + i * 256;
        outT[(size_t)idx * 32 + b] = v[i] * g[idx] * scale;
        if (cpy) cpy[b * DD + idx] = v[i];
    }
}

// materialize last-16-position K/V records [b][16][512]; pos 4095 is roped
// on the fly from kT/vT (reference ropes BOTH k and v; cache never mutated).
__global__ void fixrope_kernel(const float* __restrict__ kc, const float* __restrict__ vc,
                               const float* __restrict__ kT, const float* __restrict__ vT,
                               const float* __restrict__ cosb, const float* __restrict__ sinb,
                               float* __restrict__ kfix, float* __restrict__ vfix) {
    int idx = blockIdx.x * 256 + threadIdx.x;  // 32*16*512 = 262144
    int b = idx >> 13, rem = idx & 8191;
    int pos = rem >> 9, col = rem & 511;
    int gpos = 4080 + pos;
    float kv, vv;
    if (gpos == POS) {
        int d = col & 127, i = d >> 1;
        float c = cosb[i], s = sinb[i];
        int colp = col & ~1;
        float k0 = kT[(size_t)colp * 32 + b], k1 = kT[(size_t)(colp + 1) * 32 + b];
        float v0 = vT[(size_t)colp * 32 + b], v1 = vT[(size_t)(colp + 1) * 32 + b];
        if (d & 1) { kv = k0 * s + k1 * c; vv = v0 * s + v1 * c; }
        else       { kv = k0 * c - k1 * s; vv = v0 * c - v1 * s; }
    } else {
        size_t o = ((size_t)(b * MAXS + gpos)) * 512 + col;
        kv = kc[o]; vv = vc[o];
    }
    kfix[idx] = kv; vfix[idx] = vv;
}

// attention (r4-proven, measured 154 us): grid 1024 = (b, 32 splits of 128 pos),
// all 4 kvh per block. K/V staged via global_load_lds, double-buffered, counted
// vmcnt(8), raw barriers. 16 sub-tiles of 16 pos (8 K + 8 V).
__global__ __launch_bounds__(256, 2) void attn_stage_kernel(
    const float* __restrict__ qn, const float* __restrict__ kc, const float* __restrict__ vc,
    const float* __restrict__ kfix, const float* __restrict__ vfix,
    float* __restrict__ pml, float* __restrict__ pacc) {
    int split = blockIdx.x & 31, b = blockIdx.x >> 5;
    int tid = threadIdx.x, lane = tid & 63, wv = tid >> 6;
    __shared__ float kbuf[2][8192];   // 2 x 32 KB (16 pos x 4 kvh x 128)
    __shared__ float p_s[128][16];    // [pos][head] scores -> exp
    int qpos = tid >> 4, qhead = tid & 15;
    int qr = qpos * 4 + (qhead >> 2);          // LDS 512B-row id (0..63)
    int vh = tid >> 4, c16 = tid & 15, vkvh = vh >> 2;
    int t0 = split * SPOS;

    // q pre-rotated: qrot[j] = q[b][qhead*128 + ((j+qr)&31)*4 ..]
    float4 qrot[32];
#pragma unroll
    for (int j = 0; j < 32; ++j) {
        int g = (j + qr) & 31;
        qrot[j] = *(const float4*)(qn + (size_t)b * DD + qhead * HDIM + g * 4);
    }
    float4 av0 = {0, 0, 0, 0}, av1 = {0, 0, 0, 0};

    auto stage = [&](int t) {
        int s = t & 7;
        const float* base;
        if (t < 8) base = (split == 31 && s == 7) ? kfix + (size_t)b * 8192
                                                  : kc + ((size_t)b * MAXS + t0 + s * 16) * 512;
        else       base = (split == 31 && s == 7) ? vfix + (size_t)b * 8192
                                                  : vc + ((size_t)b * MAXS + t0 + s * 16) * 512;
        const float* g = base + wv * 2048 + lane * 4;   // per-lane global src
        float* l = &kbuf[t & 1][wv * 2048];             // wave-uniform LDS base
#pragma unroll
        for (int i = 0; i < 8; ++i)
            __builtin_amdgcn_global_load_lds(
                (const __attribute__((address_space(1))) void*)(g + i * 256),
                (__attribute__((address_space(3))) void*)(l + i * 256), 16, 0, 0);
    };

    stage(0);
    for (int t = 0; t < 16; ++t) {
        if (t < 15) { stage(t + 1); VM_WAIT8; } else { VM_WAIT0; }
        SCHED0; SBAR;
        if (t == 8) {
            // softmax: wave w handles heads 4w..4w+3 (same heads it uses in PV)
#pragma unroll
            for (int hh = 0; hh < 4; ++hh) {
                int h = wv * 4 + hh;
                float e0 = p_s[lane][h], e1 = p_s[lane + 64][h];
                float m = fmaxf(e0, e1);
#pragma unroll
                for (int off = 32; off; off >>= 1) m = fmaxf(m, __shfl_xor(m, off));
                e0 = __expf(e0 - m); e1 = __expf(e1 - m);
                p_s[lane][h] = e0; p_s[lane + 64][h] = e1;
                float l2 = e0 + e1;
#pragma unroll
                for (int off = 32; off; off >>= 1) l2 += __shfl_xor(l2, off);
                if (lane == 0) {
                    int idx = ((b * ASPLIT + split) * 16 + h) * 2;
                    pml[idx] = m; pml[idx + 1] = l2;
                }
            }
        }
        const float* kb = kbuf[t & 1];
        if (t < 8) {
            float4 acc = {0, 0, 0, 0};
            const float* rowp = kb + qr * 128;
#pragma unroll
            for (int j = 0; j < 32; ++j) {
                int g = (j + qr) & 31;
                float4 k4 = *(const float4*)(rowp + g * 4);
                acc.x = fmaf(k4.x, qrot[j].x, acc.x);
                acc.y = fmaf(k4.y, qrot[j].y, acc.y);
                acc.z = fmaf(k4.z, qrot[j].z, acc.z);
                acc.w = fmaf(k4.w, qrot[j].w, acc.w);
            }
            p_s[t * 16 + qpos][qhead] = (acc.x + acc.y + acc.z + acc.w) * SCALE;
        } else {
            int s = t - 8;
            const float* vrow = kb + vkvh * 128 + c16 * 4;
#pragma unroll
            for (int p = 0; p < 16; ++p) {
                float pw = p_s[s * 16 + p][vh];
                float4 v0 = *(const float4*)(vrow + p * 512);
                float4 v1 = *(const float4*)(vrow + p * 512 + 64);
                av0.x = fmaf(pw, v0.x, av0.x); av0.y = fmaf(pw, v0.y, av0.y);
                av0.z = fmaf(pw, v0.z, av0.z); av0.w = fmaf(pw, v0.w, av0.w);
                av1.x = fmaf(pw, v1.x, av1.x); av1.y = fmaf(pw, v1.y, av1.y);
                av1.z = fmaf(pw, v1.z, av1.z); av1.w = fmaf(pw, v1.w, av1.w);
            }
        }
        LG_WAIT0; SCHED0; SBAR;
    }
    size_t pbase = ((size_t)(b * ASPLIT + split) * 16 + vh) * HDIM;
    *(float4*)(pacc + pbase + c16 * 4) = av0;
    *(float4*)(pacc + pbase + 64 + c16 * 4) = av1;
}

// combine split partials: grid 512 = (b, h), 128 threads; writes yT
__global__ void attn_combine_kernel(const float* __restrict__ pml,
                                    const float* __restrict__ pacc, float* __restrict__ yT) {
    int bid = blockIdx.x;
    int b = bid >> 4, h = bid & 15;
    int d = threadIdx.x;
    float M = -INFINITY;
#pragma unroll 8
    for (int s = 0; s < ASPLIT; ++s)
        M = fmaxf(M, pml[((b * ASPLIT + s) * 16 + h) * 2]);
    float denom = 0.f, acc = 0.f;
#pragma unroll 4
    for (int s = 0; s < ASPLIT; ++s) {
        int idx = (b * ASPLIT + s) * 16 + h;
        float e = __expf(pml[idx * 2] - M);
        denom += pml[idx * 2 + 1] * e;
        acc += e * pacc[(size_t)idx * HDIM + d];
    }
    yT[(size_t)(h * HDIM + d) * 32 + b] = acc / denom;
}

__global__ void silu_mul_kernel(float* __restrict__ g1, const float* __restrict__ g2) {
    int i = blockIdx.x * 256 + threadIdx.x; // 262144
    float a = g1[i], bb = g2[i];
    g1[i] = a * bb / (1.f + __expf(-a));
}

extern "C" void kernel_launch(void* const* d_in, const int* in_sizes, int n_in,
                              void* d_out, int out_size, void* d_ws, size_t ws_size,
                              hipStream_t stream) {
    (void)in_sizes; (void)n_in; (void)out_size; (void)ws_size;
    const float* x    = (const float*)d_in[0];
    const float* cosb = (const float*)d_in[1];
    const float* sinb = (const float*)d_in[2];
    const float* kc   = (const float*)d_in[3];
    const float* vc   = (const float*)d_in[4];
    const float* wra  = (const float*)d_in[5];
    const float* wq   = (const float*)d_in[6];
    const float* wk   = (const float*)d_in[7];
    const float* wv   = (const float*)d_in[8];
    const float* wo   = (const float*)d_in[9];
    const float* wrf  = (const float*)d_in[10];
    const float* w1   = (const float*)d_in[11];
    const float* w2   = (const float*)d_in[12];
    const float* w3   = (const float*)d_in[13];
    float* out = (float*)d_out;
    float* ws  = (float*)d_ws;

    float* qn   = ws + OFF_QT;
    float* kT   = ws + OFF_KT;
    float* vT   = ws + OFF_VT;
    float* g1T  = ws + OFF_G1;
    float* g2T  = ws + OFF_G2;
    float* xaT  = ws + OFF_XAT;
    float* pml  = ws + OFF_PML;
    float* pacc = ws + OFF_PACC;
    float* yT   = ws + OFF_YT;
    float* h    = ws + OFF_H;
    float* xfT  = ws + OFF_XFT;
    float* kfix = ws + OFF_KFIX;
    float* vfix = ws + OFF_VFIX;

    // zero all atomic-accumulated buffers (qn,kT,vT,g1,g2 contiguous)
    zero_kernel<<<ZERO_N / 256, 256, 0, stream>>>(ws);

    // xaT = rmsnorm(x)^T, h = x
    rmsnorm_kernel<<<32, 256, 0, stream>>>(x, wra, xaT, h);
    // q (NORMAL layout), k/v (transposed for rope)
    gemv32_kernel<2048, 32, false><<<dim3(8, 64), 256, 0, stream>>>(xaT, wq, qn);
    gemv32_dual_kernel<512, 32, 2><<<dim3(4, 64), 256, 0, stream>>>(xaT, wk, wv, kT, vT);
    // patched last-16 records with rope applied to pos 4095 (cache NOT mutated)
    fixrope_kernel<<<1024, 256, 0, stream>>>(kc, vc, kT, vT, cosb, sinb, kfix, vfix);
    // attention (r4 structure, measured best)
    attn_stage_kernel<<<1024, 256, 0, stream>>>(qn, kc, vc, kfix, vfix, pml, pacc);
    attn_combine_kernel<<<512, 128, 0, stream>>>(pml, pacc, yT);
    // h = x + y @ wo
    gemv32_kernel<2048, 32, false><<<dim3(8, 64), 256, 0, stream>>>(yT, wo, h);
    // xfT = rmsnorm(h)^T, out = h
    rmsnorm_kernel<<<32, 256, 0, stream>>>(h, wrf, xfT, out);
    // g1 = xf@w1, g2 = xf@w2 (transposed outputs)
    gemv32_dual_kernel<8192, 128, 32><<<dim3(64, 16), 256, 0, stream>>>(xfT, w1, w2, g1T, g2T);
    // g1 = silu(g1)*g2 (elementwise, layout-agnostic)
    silu_mul_kernel<<<1024, 256, 0, stream>>>(g1T, g2T);
    // out += g1 @ w3
    gemv32_kernel<2048, 128, false><<<dim3(8, 64), 256, 0, stream>>>(g1T, w3, out);
}